// Round 8
// baseline (352.545 us; speedup 1.0000x reference)
//
#include <hip/hip_runtime.h>
#include <stdint.h>

// ============================================================================
// Motion_Relation_Mining — bit-exact replication of the JAX (CPU) reference.
//
// FROZEN (verified passing R0-R4, absmax 0.0): all f32 op sequences,
// NAN_POLICY_A, FMA-tanh, sequential reduce orders, radix-select semantics.
//
// R2: two-stage reductions replaced contended global atomics.
// R3: k_corr parallelized (scratch -> LDS, logs 100-wide).
// R4: k_top64 histogram de-serialized — Gaussian-clustered bins made the
//     256-bin LDS-atomic histogram serialize 64-way (1.78M bank-conflict
//     cycles). Ballot match-any aggregation: 1 atomic per (wave, bin)
//     instead of per lane. Counts identical (exact integers). Also
//     __launch_bounds__(1024,1) so enc[64] stays in VGPRs, not scratch.
// ============================================================================

typedef unsigned int u32;
typedef unsigned long long u64;

// sizes
#define BB 4
#define TT 8
#define CC 16
#define HWN 65536              // H*W
#define NF 7
#define FRAME 1048576LL        // C*H*W
#define NELF 7340032.0f        // nf*C*H*W per batch (exact in f32)
#define NPAIR 28
#define SEG 65536

// ws layout (bytes)
#define WS_MM 0                // u32[24] final min/max (encoded)
#define WS_CORR 128            // float[4]
#define WS_HIST 512            // u32[4][300] final histograms
#define WS_TOP 8192            // int[28][64]
#define WS_MAG 16384           // float[28][65536]
// overlaid inside WS_MAG region — fully consumed before k_mag writes:
#define WS_MMPART (WS_MAG)            // u32[2048][6]  = 48 KiB
#define WS_HISTC  (WS_MAG + 65536)    // u32[4][64][300] = 300 KiB
#define WS_NEED (16384 + 28LL*65536*4)

__device__ __forceinline__ u32 encf(float f) {
  u32 u = __float_as_uint(f);
  return (u & 0x80000000u) ? ~u : (u | 0x80000000u);
}
__device__ __forceinline__ float decf(u32 e) {
  u32 u = (e & 0x80000000u) ? (e ^ 0x80000000u) : ~e;
  return __uint_as_float(u);
}

// zero the 64x4 histogram copies (required each call: graph replays)
__global__ void k_init(u32* histc) {
  int i = blockIdx.x * 256 + threadIdx.x;
  if (i < 76800) histc[i] = 0u;
}

// ---- single pass over frames: per-batch min/max of x_t, x_t1, x_t*x_t1.
__global__ void k_minmax_pass(const float* __restrict__ x, u32* __restrict__ part) {
  const int blk = blockIdx.x;            // 2048 blocks: 512 per batch
  const int b = blk >> 9;
  const long long w0 = (long long)(blk & 511) * 2048;
  const int tid = threadIdx.x;
  u32 mn0 = 0xFFFFFFFFu, mx0 = 0u, mn1 = 0xFFFFFFFFu, mx1 = 0u,
      mnp = 0xFFFFFFFFu, mxp = 0u;
  float prev[8];
  for (int t = 0; t < 8; ++t) {
    const float* fp = x + ((long long)(b * TT + t)) * FRAME + w0 + tid;
#pragma unroll
    for (int k = 0; k < 8; ++k) {
      float v = fp[k << 8];
      u32 ev = encf(v);
      if (t < 7) { mn0 = min(mn0, ev); mx0 = max(mx0, ev); }   // x_t view
      if (t > 0) {                                             // x_t1 view + product
        mn1 = min(mn1, ev); mx1 = max(mx1, ev);
        u32 ep = encf(__fmul_rn(prev[k], v));
        mnp = min(mnp, ep); mxp = max(mxp, ep);
      }
      prev[k] = v;
    }
  }
  __shared__ u32 sm[6][256];
  sm[0][tid] = mn0; sm[1][tid] = mx0; sm[2][tid] = mn1;
  sm[3][tid] = mx1; sm[4][tid] = mnp; sm[5][tid] = mxp;
  __syncthreads();
  for (int st = 128; st > 0; st >>= 1) {
    if (tid < st) {
      sm[0][tid] = min(sm[0][tid], sm[0][tid + st]);
      sm[1][tid] = max(sm[1][tid], sm[1][tid + st]);
      sm[2][tid] = min(sm[2][tid], sm[2][tid + st]);
      sm[3][tid] = max(sm[3][tid], sm[3][tid + st]);
      sm[4][tid] = min(sm[4][tid], sm[4][tid + st]);
      sm[5][tid] = max(sm[5][tid], sm[5][tid + st]);
    }
    __syncthreads();
  }
  if (tid == 0) {
    u32* o = part + blk * 6;
    o[0] = sm[0][0]; o[1] = sm[1][0]; o[2] = sm[2][0];
    o[3] = sm[3][0]; o[4] = sm[4][0]; o[5] = sm[5][0];
  }
}

// 4 blocks (one per batch): reduce 512 partials -> mm[b*6..]
__global__ void k_mm_reduce(const u32* __restrict__ part, u32* __restrict__ mm) {
  const int b = blockIdx.x;
  const int tid = threadIdx.x;
  const u32* p0 = part + (b * 512 + tid) * 6;
  const u32* p1 = p0 + 256 * 6;
  __shared__ u32 sm[6][256];
  sm[0][tid] = min(p0[0], p1[0]); sm[1][tid] = max(p0[1], p1[1]);
  sm[2][tid] = min(p0[2], p1[2]); sm[3][tid] = max(p0[3], p1[3]);
  sm[4][tid] = min(p0[4], p1[4]); sm[5][tid] = max(p0[5], p1[5]);
  __syncthreads();
  for (int st = 128; st > 0; st >>= 1) {
    if (tid < st) {
      sm[0][tid] = min(sm[0][tid], sm[0][tid + st]);
      sm[1][tid] = max(sm[1][tid], sm[1][tid + st]);
      sm[2][tid] = min(sm[2][tid], sm[2][tid + st]);
      sm[3][tid] = max(sm[3][tid], sm[3][tid + st]);
      sm[4][tid] = min(sm[4][tid], sm[4][tid + st]);
      sm[5][tid] = max(sm[5][tid], sm[5][tid + st]);
    }
    __syncthreads();
  }
  if (tid == 0)
    for (int i = 0; i < 6; ++i) mm[b * 6 + i] = sm[i][0];
}

__device__ __forceinline__ int bin_of(float v, float vmin, float den) {
  float tt = __fsub_rn(v, vmin);
  float q = __fdiv_rn(tt, den);
  float z = __fmul_rn(q, 100.0f);
  z = fminf(fmaxf(z, 0.0f), 99.0f);
  return (int)z;
}

// ---- single pass over frames: LDS hist -> one of 64 global copies per batch
__global__ void k_hist_pass(const float* __restrict__ x, const u32* __restrict__ mm,
                            u32* __restrict__ histc) {
  __shared__ u32 h[300];
  for (int i = threadIdx.x; i < 300; i += 256) h[i] = 0u;
  __syncthreads();
  const int blk = blockIdx.x;
  const int b = blk >> 9;
  const long long w0 = (long long)(blk & 511) * 2048;
  const int tid = threadIdx.x;
  float mn_t = decf(mm[6 * b + 0]), den_t = __fsub_rn(decf(mm[6 * b + 1]), decf(mm[6 * b + 0]));
  float mn_1 = decf(mm[6 * b + 2]), den_1 = __fsub_rn(decf(mm[6 * b + 3]), decf(mm[6 * b + 2]));
  float mn_p = decf(mm[6 * b + 4]), den_p = __fsub_rn(decf(mm[6 * b + 5]), decf(mm[6 * b + 4]));
  float prev[8];
  for (int t = 0; t < 8; ++t) {
    const float* fp = x + ((long long)(b * TT + t)) * FRAME + w0 + tid;
#pragma unroll
    for (int k = 0; k < 8; ++k) {
      float v = fp[k << 8];
      if (t < 7) atomicAdd(&h[bin_of(v, mn_t, den_t)], 1u);
      if (t > 0) {
        atomicAdd(&h[100 + bin_of(v, mn_1, den_1)], 1u);
        float p = __fmul_rn(prev[k], v);
        atomicAdd(&h[200 + bin_of(p, mn_p, den_p)], 1u);
      }
      prev[k] = v;
    }
  }
  __syncthreads();
  u32* dst = histc + ((b << 6) + (blk & 63)) * 300;
  for (int i = threadIdx.x; i < 300; i += 256) atomicAdd(&dst[i], h[i]);
}

// 4 blocks x 320 threads: hist[b*300+i] = sum of 64 copies (exact integers)
__global__ void k_hist_reduce(const u32* __restrict__ histc, u32* __restrict__ hist) {
  int b = blockIdx.x, i = threadIdx.x;
  if (i < 300) {
    const u32* src = histc + (b << 6) * 300 + i;
    u32 s = 0;
    for (int c = 0; c < 64; ++c) s += src[c * 300];
    hist[b * 300 + i] = s;
  }
}

// Eigen/XLA fast-tanh rational interpolant (FMA form) — FROZEN
__device__ float tanh_emul(float a) {
  const float kClamp = 7.90531110763549805f;
  float xx = fminf(fmaxf(a, -kClamp), kClamp);
  float x2 = __fmul_rn(xx, xx);
  float p = __fmaf_rn(x2, -2.76076847742355e-16f, 2.00018790482477e-13f);
  p = __fmaf_rn(x2, p, -8.60467152213735e-11f);
  p = __fmaf_rn(x2, p, 5.12229709037114e-08f);
  p = __fmaf_rn(x2, p, 1.48572235717979e-05f);
  p = __fmaf_rn(x2, p, 6.37261928875436e-04f);
  p = __fmaf_rn(x2, p, 4.89352455891786e-03f);
  p = __fmul_rn(xx, p);
  float q = __fmaf_rn(x2, 1.19825839466702e-06f, 1.18534705686654e-04f);
  q = __fmaf_rn(x2, q, 2.26843463243900e-03f);
  q = __fmaf_rn(x2, q, 4.89352518554385e-03f);
  float r = __fdiv_rn(p, q);
  if (fabsf(a) < 0.0004f) r = a;
  return r;
}

// ---- mi + corr per batch. Parallel per-bin terms, FROZEN sequential chains.
__global__ void __launch_bounds__(128) k_corr(const u32* __restrict__ hist,
                                              float* __restrict__ corr) {
  const int b = blockIdx.x;
  const int tid = threadIdx.x;
  __shared__ float shx[100], shx1[100], sterm[100];
  __shared__ float ssum[3];
  const u32* HX = hist + b * 300;
  const u32* HX1 = HX + 100;
  const u32* HJ = HX + 200;

  if (tid < 100) {
    shx[tid] = __fdiv_rn((float)HX[tid], NELF);
    shx1[tid] = __fdiv_rn((float)HX1[tid], NELF);
  }
  __syncthreads();
  if (tid == 0) {
    float Sj = 0.0f;
    for (int i = 0; i < 100; ++i) Sj = __fadd_rn(Sj, (float)HJ[i]);
    float Sx = 0.0f, Sx1 = 0.0f;
    for (int i = 0; i < 100; ++i) Sx = __fadd_rn(Sx, shx[i]);
    for (int i = 0; i < 100; ++i) Sx1 = __fadd_rn(Sx1, shx1[i]);
    ssum[0] = Sj; ssum[1] = Sx; ssum[2] = Sx1;
  }
  __syncthreads();
  if (tid < 100) {
    float Sj = ssum[0], Sx = ssum[1], Sx1 = ssum[2];
    float pj = __fdiv_rn((float)HJ[tid], Sj);
    float px = __fdiv_rn(shx[tid], Sx);
    float px1 = __fdiv_rn(shx1[tid], Sx1);
    float la = (float)log((double)__fadd_rn(pj, 1e-10f));
    float lb = (float)log((double)__fadd_rn(__fmul_rn(px, px1), 1e-10f));
    sterm[tid] = __fmul_rn(pj, __fsub_rn(la, lb));
  }
  __syncthreads();
  if (tid == 0) {
    float mi = 0.0f;
    for (int i = 0; i < 100; ++i) mi = __fadd_rn(mi, sterm[i]);
    float lm = (float)log((double)mi);
    float th = tanh_emul(lm);
    float num = (float)exp(0.8);
    corr[b] = __fdiv_rn(num, th);
  }
}

// ---- mag[b,f,s] = sequential f32 sum over c of fl(fl(x1-x0)+corr[b]) — FROZEN
__global__ void k_mag(const float* __restrict__ x, const float* __restrict__ corr,
                      float* __restrict__ mag) {
  int gid = blockIdx.x * 256 + threadIdx.x;
  int bf = gid >> 16;
  int s = gid & 65535;
  int b = bf / NF, f = bf % NF;
  int g = s >> 6, i = (s >> 3) & 7, j = s & 7;
  int gy = g >> 5, gx = g & 31;
  int hw = (gy * 8 + i) * 256 + gx * 8 + j;
  const float cb = corr[b];
  long long base = ((long long)(b * TT + f)) * FRAME + hw;
  float acc = 0.0f;
  for (int c = 0; c < CC; ++c) {
    float a0 = x[base + (long long)c * HWN];
    float a1 = x[base + FRAME + (long long)c * HWN];
    acc = __fadd_rn(acc, __fadd_rn(__fsub_rn(a1, a0), cb));
  }
  mag[gid] = acc;
}

// ---- top-64 per (b,f): MSB-first radix-select — FROZEN semantics.
// R4: ballot match-any histogram (1 atomic per wave-bin group, not per lane).
__global__ void __launch_bounds__(1024, 1) k_top64(const float* __restrict__ mag,
                                                   int* __restrict__ top) {
  int bf = blockIdx.x;
  const float* m = mag + (long long)bf * SEG;
  int tid = threadIdx.x;
  int lane = tid & 63;
  __shared__ u32 bins[256];
  __shared__ u64 sel[64];
  __shared__ u32 tie[2048];
  __shared__ u32 scal[4];

  u32 enc[64];
#pragma unroll
  for (int k = 0; k < 64; ++k) enc[k] = encf(m[tid + (k << 10)]);

  u32 prefix = 0u, need = 64u;
  for (int pass = 0; pass < 4; ++pass) {
    int shift = 24 - pass * 8;
    if (tid < 256) bins[tid] = 0u;
    __syncthreads();
#pragma unroll 8
    for (int k = 0; k < 64; ++k) {
      u32 e = enc[k];
      bool ok = (pass == 0) || ((e >> (shift + 8)) == (prefix >> (shift + 8)));
      u32 bin = (e >> shift) & 0xFFu;
      // peer mask: ok-lanes in this wave with the same bin (match-any)
      u64 pm = __ballot(ok);
#pragma unroll
      for (int bit = 0; bit < 8; ++bit) {
        u64 v = __ballot((bin >> bit) & 1u);
        pm &= ((bin >> bit) & 1u) ? v : ~v;
      }
      if (ok && lane == (__ffsll((unsigned long long)pm) - 1))
        atomicAdd(&bins[bin], (u32)__popcll(pm));
    }
    __syncthreads();
    if (tid == 0) {
      u32 cum = 0; int d = 255;
      for (; d >= 0; --d) {
        u32 c = bins[d];
        if (cum + c >= need) break;
        cum += c;
      }
      if (d < 0) d = 0;
      scal[0] = prefix | ((u32)d << shift);
      scal[1] = need - cum;
      scal[2] = 0u; scal[3] = 0u;
    }
    __syncthreads();
    prefix = scal[0]; need = scal[1];
    __syncthreads();
  }

#pragma unroll 8
  for (int k = 0; k < 64; ++k) {
    u32 e = enc[k];
    int s = tid + (k << 10);
    if (e > prefix) {
      u32 p = atomicAdd(&scal[2], 1u);
      sel[p] = ((u64)e << 32) | (u64)(0xFFFFFFFFu - (u32)s);
    } else if (e == prefix) {
      u32 p = atomicAdd(&scal[3], 1u);
      if (p < 2048u) tie[p] = (u32)s;
    }
  }
  __syncthreads();
  int tc = (int)scal[3];
  int k2 = (int)need;
  for (int i = tid; i < tc; i += 1024) {
    u32 si = tie[i];
    int rank = 0;
    for (int j = 0; j < tc; ++j) rank += (tie[j] < si);
    if (rank < k2) {
      u32 p = atomicAdd(&scal[2], 1u);
      sel[p] = ((u64)prefix << 32) | (u64)(0xFFFFFFFFu - si);
    }
  }
  __syncthreads();
  if (tid < 64) {
    u64 mine = sel[tid];
    int rank = 0;
    for (int j = 0; j < 64; ++j) rank += (sel[j] > mine);
    int s = (int)(0xFFFFFFFFu - (u32)(mine & 0xFFFFFFFFull));
    top[bf * 64 + rank] = s;
  }
}

// ---- centers -> cov -> inv -> maha -> radix-select top-169 -> graph — FROZEN
__global__ void __launch_bounds__(256) k_graph(const int* __restrict__ top,
                                               float* __restrict__ out) {
  int bf = blockIdx.x;
  int tid = threadIdx.x;
  __shared__ float cy[64], cx[64];
  __shared__ float inv[4];
  __shared__ u32 keys[4096];
  __shared__ u32 bins[256];
  __shared__ u32 tie[4096];
  __shared__ u32 scal[4];
  if (tid < 64) {
    int idx = top[bf * 64 + tid];
    cy[tid] = (float)((idx >> 6) * 8 + 4);
    cx[tid] = (float)((idx & 63) * 8 + 4);
  }
  __syncthreads();
  if (tid == 0) {
    float sy = 0.f, sx = 0.f;
    for (int r = 0; r < 64; ++r) sy = __fadd_rn(sy, cy[r]);
    for (int r = 0; r < 64; ++r) sx = __fadd_rn(sx, cx[r]);
    float my = __fdiv_rn(sy, 64.0f), mx = __fdiv_rn(sx, 64.0f);
    float c00 = 0.f, c01 = 0.f, c11 = 0.f;
    for (int r = 0; r < 64; ++r) {
      float dy = __fsub_rn(cy[r], my);
      float dx = __fsub_rn(cx[r], mx);
      c00 = __fadd_rn(c00, __fmul_rn(dy, dy));
      c01 = __fadd_rn(c01, __fmul_rn(dy, dx));
      c11 = __fadd_rn(c11, __fmul_rn(dx, dx));
    }
    c00 = __fdiv_rn(c00, 63.0f); c01 = __fdiv_rn(c01, 63.0f); c11 = __fdiv_rn(c11, 63.0f);
    c00 = __fadd_rn(c00, 1e-6f); c11 = __fadd_rn(c11, 1e-6f);
    double det = (double)c00 * (double)c11 - (double)c01 * (double)c01;
    inv[0] = (float)((double)c11 / det);
    inv[1] = (float)(-(double)c01 / det);
    inv[2] = inv[1];
    inv[3] = (float)((double)c00 / det);
  }
  __syncthreads();
  float i00 = inv[0], i01 = inv[1], i10 = inv[2], i11 = inv[3];
  long long obase = (long long)bf * 4096;
  for (int e = tid; e < 4096; e += 256) {
    int q = e >> 6, r = e & 63;
    float d0 = __fsub_rn(cy[r], cy[q]);
    float d1 = __fsub_rn(cx[r], cx[q]);
    float v0 = __fadd_rn(__fadd_rn(0.0f, __fmul_rn(d0, i00)), __fmul_rn(d1, i10));
    float v1 = __fadd_rn(__fadd_rn(0.0f, __fmul_rn(d0, i01)), __fmul_rn(d1, i11));
    float p0 = __fmul_rn(v0, d0);
    float p1 = __fmul_rn(v1, d1);
    float s0 = __fsqrt_rn(p0);
    float s1 = __fsqrt_rn(p1);
    float mh = __fadd_rn(__fadd_rn(0.0f, s0), s1);
    u32 key;
    if (mh != mh) key = 0xFFFFFFFFu;
    else key = encf(-mh);
    keys[e] = key;
    out[obase + e] = 0.0f;
  }
  __syncthreads();

  u32 prefix = 0u, need = 169u;
  for (int pass = 0; pass < 4; ++pass) {
    int shift = 24 - pass * 8;
    if (tid == 0) { scal[2] = 0u; }
    bins[tid] = 0u;
    __syncthreads();
    for (int k = 0; k < 16; ++k) {
      u32 ky = keys[tid + (k << 8)];
      bool ok = (pass == 0) || ((ky >> (shift + 8)) == (prefix >> (shift + 8)));
      if (ok) atomicAdd(&bins[(ky >> shift) & 0xFFu], 1u);
    }
    __syncthreads();
    if (tid == 0) {
      u32 cum = 0; int d = 255;
      for (; d >= 0; --d) {
        u32 c = bins[d];
        if (cum + c >= need) break;
        cum += c;
      }
      if (d < 0) d = 0;
      scal[0] = prefix | ((u32)d << shift);
      scal[1] = need - cum;
    }
    __syncthreads();
    prefix = scal[0]; need = scal[1];
    __syncthreads();
  }

  for (int k = 0; k < 16; ++k) {
    int e = tid + (k << 8);
    u32 ky = keys[e];
    if (ky > prefix) out[obase + e] = 1.0f;
    else if (ky == prefix) {
      u32 p = atomicAdd(&scal[2], 1u);
      tie[p] = (u32)e;
    }
  }
  __syncthreads();
  int tc = (int)scal[2];
  for (int i = tid; i < tc; i += 256) {
    u32 ei = tie[i];
    int rank = 0;
    for (int j = 0; j < tc; ++j) rank += (tie[j] < ei);
    if (rank < (int)need) out[obase + ei] = 1.0f;
  }
}

extern "C" void kernel_launch(void* const* d_in, const int* in_sizes, int n_in,
                              void* d_out, int out_size, void* d_ws, size_t ws_size,
                              hipStream_t stream) {
  if (ws_size < (size_t)WS_NEED) return;
  const float* x = (const float*)d_in[0];
  float* out = (float*)d_out;
  char* ws = (char*)d_ws;
  u32* mm = (u32*)(ws + WS_MM);
  float* corr = (float*)(ws + WS_CORR);
  u32* hist = (u32*)(ws + WS_HIST);
  int* top = (int*)(ws + WS_TOP);
  float* mag = (float*)(ws + WS_MAG);
  u32* mmpart = (u32*)(ws + WS_MMPART);
  u32* histc = (u32*)(ws + WS_HISTC);

  hipLaunchKernelGGL(k_init, dim3(300), dim3(256), 0, stream, histc);
  hipLaunchKernelGGL(k_minmax_pass, dim3(2048), dim3(256), 0, stream, x, mmpart);
  hipLaunchKernelGGL(k_mm_reduce, dim3(4), dim3(256), 0, stream, mmpart, mm);
  hipLaunchKernelGGL(k_hist_pass, dim3(2048), dim3(256), 0, stream, x, mm, histc);
  hipLaunchKernelGGL(k_hist_reduce, dim3(4), dim3(320), 0, stream, histc, hist);
  hipLaunchKernelGGL(k_corr, dim3(4), dim3(128), 0, stream, hist, corr);
  hipLaunchKernelGGL(k_mag, dim3(7168), dim3(256), 0, stream, x, corr, mag);
  hipLaunchKernelGGL(k_top64, dim3(28), dim3(1024), 0, stream, mag, top);
  hipLaunchKernelGGL(k_graph, dim3(28), dim3(256), 0, stream, top, out);
}

// Round 9
// 284.209 us; speedup vs baseline: 1.2404x; 1.2404x over previous
//
#include <hip/hip_runtime.h>
#include <stdint.h>

// ============================================================================
// Motion_Relation_Mining — bit-exact replication of the JAX (CPU) reference.
//
// FROZEN (verified passing R0-R8, absmax 0.0): all f32 op sequences,
// NAN_POLICY_A, FMA-tanh, sequential reduce orders, selection key
// (enc(value)<<32)|~idx i.e. (value desc, index asc).
//
// R2: two-stage reductions replaced contended global atomics.
// R3: k_corr parallelized (scratch -> LDS, logs 100-wide).
// R4 (FAILED, reverted): ballot match-any histogram — fixed bank conflicts
//     but #pragma unroll 8 sent enc[64] to scratch (VGPR 64->20, FETCH +3MB)
//     and 2300 serial ballots/thread. Net regression 133->188us.
// R8: k_top64 restructured: 8 blocks/(b,f) x 8 regs/thread; 64th-largest
//     value found by 32-round bitwise threshold search (register compares +
//     shfl reduce, ONE barrier/round, zero LDS atomics, zero scratch).
//     Candidates (enc>=T, superset of top-64) -> d_out scratch -> exact
//     rank merge. k_minmax_pass vectorized to float4 (order-free ops).
// ============================================================================

typedef unsigned int u32;
typedef unsigned long long u64;

// sizes
#define BB 4
#define TT 8
#define CC 16
#define HWN 65536              // H*W
#define NF 7
#define FRAME 1048576LL        // C*H*W
#define NELF 7340032.0f        // nf*C*H*W per batch (exact in f32)
#define NPAIR 28
#define SEG 65536

// ws layout (bytes)
#define WS_MM 0                // u32[24] final min/max (encoded)
#define WS_CORR 128            // float[4]
#define WS_CCNT 144            // u32[28] candidate counters (zeroed by k_init)
#define WS_HIST 512            // u32[4][300] final histograms
#define WS_TOP 8192            // int[28][64]
#define WS_MAG 16384           // float[28][65536]
// overlaid inside WS_MAG region — fully consumed before k_mag writes:
#define WS_MMPART (WS_MAG)            // u32[2048][6]  = 48 KiB
#define WS_HISTC  (WS_MAG + 65536)    // u32[4][64][300] = 300 KiB
#define WS_NEED (16384 + 28LL*65536*4)
// candidate buffer lives in d_out (28*2048 u64 = 448 KiB = exact out size);
// k_graph fully overwrites d_out afterwards.

__device__ __forceinline__ u32 encf(float f) {
  u32 u = __float_as_uint(f);
  return (u & 0x80000000u) ? ~u : (u | 0x80000000u);
}
__device__ __forceinline__ float decf(u32 e) {
  u32 u = (e & 0x80000000u) ? (e ^ 0x80000000u) : ~e;
  return __uint_as_float(u);
}

// zero the histogram copies + candidate counters (graph replays each call)
__global__ void k_init(u32* histc, u32* ccnt) {
  int i = blockIdx.x * 256 + threadIdx.x;
  if (i < 76800) histc[i] = 0u;
  if (i < 28) ccnt[i] = 0u;
}

// ---- single pass over frames: per-batch min/max of x_t, x_t1, x_t*x_t1.
// R8: float4 loads. min/max are order-free; product is elementwise -> exact.
__global__ void k_minmax_pass(const float* __restrict__ x, u32* __restrict__ part) {
  const int blk = blockIdx.x;            // 2048 blocks: 512 per batch
  const int b = blk >> 9;
  const long long w0 = (long long)(blk & 511) * 2048;
  const int tid = threadIdx.x;
  u32 mn0 = 0xFFFFFFFFu, mx0 = 0u, mn1 = 0xFFFFFFFFu, mx1 = 0u,
      mnp = 0xFFFFFFFFu, mxp = 0u;
  float4 pv0, pv1;
  for (int t = 0; t < 8; ++t) {
    const float4* fp = (const float4*)(x + ((long long)(b * TT + t)) * FRAME + w0);
    float4 v0 = fp[tid];
    float4 v1 = fp[tid + 256];
#define MM_COMP(vc, pc)                                                     \
    {                                                                       \
      u32 ev = encf(vc);                                                    \
      if (t < 7) { mn0 = min(mn0, ev); mx0 = max(mx0, ev); }                \
      if (t > 0) {                                                          \
        mn1 = min(mn1, ev); mx1 = max(mx1, ev);                             \
        u32 ep = encf(__fmul_rn(pc, vc));                                   \
        mnp = min(mnp, ep); mxp = max(mxp, ep);                             \
      }                                                                     \
    }
    MM_COMP(v0.x, pv0.x) MM_COMP(v0.y, pv0.y) MM_COMP(v0.z, pv0.z) MM_COMP(v0.w, pv0.w)
    MM_COMP(v1.x, pv1.x) MM_COMP(v1.y, pv1.y) MM_COMP(v1.z, pv1.z) MM_COMP(v1.w, pv1.w)
#undef MM_COMP
    pv0 = v0; pv1 = v1;
  }
  __shared__ u32 sm[6][256];
  sm[0][tid] = mn0; sm[1][tid] = mx0; sm[2][tid] = mn1;
  sm[3][tid] = mx1; sm[4][tid] = mnp; sm[5][tid] = mxp;
  __syncthreads();
  for (int st = 128; st > 0; st >>= 1) {
    if (tid < st) {
      sm[0][tid] = min(sm[0][tid], sm[0][tid + st]);
      sm[1][tid] = max(sm[1][tid], sm[1][tid + st]);
      sm[2][tid] = min(sm[2][tid], sm[2][tid + st]);
      sm[3][tid] = max(sm[3][tid], sm[3][tid + st]);
      sm[4][tid] = min(sm[4][tid], sm[4][tid + st]);
      sm[5][tid] = max(sm[5][tid], sm[5][tid + st]);
    }
    __syncthreads();
  }
  if (tid == 0) {
    u32* o = part + blk * 6;
    o[0] = sm[0][0]; o[1] = sm[1][0]; o[2] = sm[2][0];
    o[3] = sm[3][0]; o[4] = sm[4][0]; o[5] = sm[5][0];
  }
}

// 4 blocks (one per batch): reduce 512 partials -> mm[b*6..]
__global__ void k_mm_reduce(const u32* __restrict__ part, u32* __restrict__ mm) {
  const int b = blockIdx.x;
  const int tid = threadIdx.x;
  const u32* p0 = part + (b * 512 + tid) * 6;
  const u32* p1 = p0 + 256 * 6;
  __shared__ u32 sm[6][256];
  sm[0][tid] = min(p0[0], p1[0]); sm[1][tid] = max(p0[1], p1[1]);
  sm[2][tid] = min(p0[2], p1[2]); sm[3][tid] = max(p0[3], p1[3]);
  sm[4][tid] = min(p0[4], p1[4]); sm[5][tid] = max(p0[5], p1[5]);
  __syncthreads();
  for (int st = 128; st > 0; st >>= 1) {
    if (tid < st) {
      sm[0][tid] = min(sm[0][tid], sm[0][tid + st]);
      sm[1][tid] = max(sm[1][tid], sm[1][tid + st]);
      sm[2][tid] = min(sm[2][tid], sm[2][tid + st]);
      sm[3][tid] = max(sm[3][tid], sm[3][tid + st]);
      sm[4][tid] = min(sm[4][tid], sm[4][tid + st]);
      sm[5][tid] = max(sm[5][tid], sm[5][tid + st]);
    }
    __syncthreads();
  }
  if (tid == 0)
    for (int i = 0; i < 6; ++i) mm[b * 6 + i] = sm[i][0];
}

__device__ __forceinline__ int bin_of(float v, float vmin, float den) {
  float tt = __fsub_rn(v, vmin);
  float q = __fdiv_rn(tt, den);
  float z = __fmul_rn(q, 100.0f);
  z = fminf(fmaxf(z, 0.0f), 99.0f);
  return (int)z;
}

// ---- single pass over frames: LDS hist -> one of 64 global copies per batch
__global__ void k_hist_pass(const float* __restrict__ x, const u32* __restrict__ mm,
                            u32* __restrict__ histc) {
  __shared__ u32 h[300];
  for (int i = threadIdx.x; i < 300; i += 256) h[i] = 0u;
  __syncthreads();
  const int blk = blockIdx.x;
  const int b = blk >> 9;
  const long long w0 = (long long)(blk & 511) * 2048;
  const int tid = threadIdx.x;
  float mn_t = decf(mm[6 * b + 0]), den_t = __fsub_rn(decf(mm[6 * b + 1]), decf(mm[6 * b + 0]));
  float mn_1 = decf(mm[6 * b + 2]), den_1 = __fsub_rn(decf(mm[6 * b + 3]), decf(mm[6 * b + 2]));
  float mn_p = decf(mm[6 * b + 4]), den_p = __fsub_rn(decf(mm[6 * b + 5]), decf(mm[6 * b + 4]));
  float prev[8];
  for (int t = 0; t < 8; ++t) {
    const float* fp = x + ((long long)(b * TT + t)) * FRAME + w0 + tid;
#pragma unroll
    for (int k = 0; k < 8; ++k) {
      float v = fp[k << 8];
      if (t < 7) atomicAdd(&h[bin_of(v, mn_t, den_t)], 1u);
      if (t > 0) {
        atomicAdd(&h[100 + bin_of(v, mn_1, den_1)], 1u);
        float p = __fmul_rn(prev[k], v);
        atomicAdd(&h[200 + bin_of(p, mn_p, den_p)], 1u);
      }
      prev[k] = v;
    }
  }
  __syncthreads();
  u32* dst = histc + ((b << 6) + (blk & 63)) * 300;
  for (int i = threadIdx.x; i < 300; i += 256) atomicAdd(&dst[i], h[i]);
}

// 4 blocks x 320 threads: hist[b*300+i] = sum of 64 copies (exact integers)
__global__ void k_hist_reduce(const u32* __restrict__ histc, u32* __restrict__ hist) {
  int b = blockIdx.x, i = threadIdx.x;
  if (i < 300) {
    const u32* src = histc + (b << 6) * 300 + i;
    u32 s = 0;
    for (int c = 0; c < 64; ++c) s += src[c * 300];
    hist[b * 300 + i] = s;
  }
}

// Eigen/XLA fast-tanh rational interpolant (FMA form) — FROZEN
__device__ float tanh_emul(float a) {
  const float kClamp = 7.90531110763549805f;
  float xx = fminf(fmaxf(a, -kClamp), kClamp);
  float x2 = __fmul_rn(xx, xx);
  float p = __fmaf_rn(x2, -2.76076847742355e-16f, 2.00018790482477e-13f);
  p = __fmaf_rn(x2, p, -8.60467152213735e-11f);
  p = __fmaf_rn(x2, p, 5.12229709037114e-08f);
  p = __fmaf_rn(x2, p, 1.48572235717979e-05f);
  p = __fmaf_rn(x2, p, 6.37261928875436e-04f);
  p = __fmaf_rn(x2, p, 4.89352455891786e-03f);
  p = __fmul_rn(xx, p);
  float q = __fmaf_rn(x2, 1.19825839466702e-06f, 1.18534705686654e-04f);
  q = __fmaf_rn(x2, q, 2.26843463243900e-03f);
  q = __fmaf_rn(x2, q, 4.89352518554385e-03f);
  float r = __fdiv_rn(p, q);
  if (fabsf(a) < 0.0004f) r = a;
  return r;
}

// ---- mi + corr per batch. Parallel per-bin terms, FROZEN sequential chains.
__global__ void __launch_bounds__(128) k_corr(const u32* __restrict__ hist,
                                              float* __restrict__ corr) {
  const int b = blockIdx.x;
  const int tid = threadIdx.x;
  __shared__ float shx[100], shx1[100], sterm[100];
  __shared__ float ssum[3];
  const u32* HX = hist + b * 300;
  const u32* HX1 = HX + 100;
  const u32* HJ = HX + 200;

  if (tid < 100) {
    shx[tid] = __fdiv_rn((float)HX[tid], NELF);
    shx1[tid] = __fdiv_rn((float)HX1[tid], NELF);
  }
  __syncthreads();
  if (tid == 0) {
    float Sj = 0.0f;
    for (int i = 0; i < 100; ++i) Sj = __fadd_rn(Sj, (float)HJ[i]);
    float Sx = 0.0f, Sx1 = 0.0f;
    for (int i = 0; i < 100; ++i) Sx = __fadd_rn(Sx, shx[i]);
    for (int i = 0; i < 100; ++i) Sx1 = __fadd_rn(Sx1, shx1[i]);
    ssum[0] = Sj; ssum[1] = Sx; ssum[2] = Sx1;
  }
  __syncthreads();
  if (tid < 100) {
    float Sj = ssum[0], Sx = ssum[1], Sx1 = ssum[2];
    float pj = __fdiv_rn((float)HJ[tid], Sj);
    float px = __fdiv_rn(shx[tid], Sx);
    float px1 = __fdiv_rn(shx1[tid], Sx1);
    float la = (float)log((double)__fadd_rn(pj, 1e-10f));
    float lb = (float)log((double)__fadd_rn(__fmul_rn(px, px1), 1e-10f));
    sterm[tid] = __fmul_rn(pj, __fsub_rn(la, lb));
  }
  __syncthreads();
  if (tid == 0) {
    float mi = 0.0f;
    for (int i = 0; i < 100; ++i) mi = __fadd_rn(mi, sterm[i]);
    float lm = (float)log((double)mi);
    float th = tanh_emul(lm);
    float num = (float)exp(0.8);
    corr[b] = __fdiv_rn(num, th);
  }
}

// ---- mag[b,f,s] = sequential f32 sum over c of fl(fl(x1-x0)+corr[b]) — FROZEN
__global__ void k_mag(const float* __restrict__ x, const float* __restrict__ corr,
                      float* __restrict__ mag) {
  int gid = blockIdx.x * 256 + threadIdx.x;
  int bf = gid >> 16;
  int s = gid & 65535;
  int b = bf / NF, f = bf % NF;
  int g = s >> 6, i = (s >> 3) & 7, j = s & 7;
  int gy = g >> 5, gx = g & 31;
  int hw = (gy * 8 + i) * 256 + gx * 8 + j;
  const float cb = corr[b];
  long long base = ((long long)(b * TT + f)) * FRAME + hw;
  float acc = 0.0f;
  for (int c = 0; c < CC; ++c) {
    float a0 = x[base + (long long)c * HWN];
    float a1 = x[base + FRAME + (long long)c * HWN];
    acc = __fadd_rn(acc, __fadd_rn(__fsub_rn(a1, a0), cb));
  }
  mag[gid] = acc;
}

// ---- top-64 stage 1: 8 blocks per (b,f), 8192 elements each.
// Bitwise threshold search for the local 64th-largest VALUE (register
// compares + shfl reduce + 1 barrier/round, double-buffered wave counts).
// Emits all elements with enc >= T_local (>= 64, provable superset of the
// global top-64 members in this sub-range) to the candidate buffer.
__global__ void __launch_bounds__(1024) k_top64_local(const float* __restrict__ mag,
                                                      u64* __restrict__ cand,
                                                      u32* __restrict__ ccnt) {
  const int blk = blockIdx.x;        // 224: 8 per bf
  const int bf = blk >> 3;
  const int sub = blk & 7;
  const int tid = threadIdx.x;
  const int lane = tid & 63;
  const int wid = tid >> 6;          // 0..15
  const float4* m4 = (const float4*)(mag + (long long)bf * SEG + (long long)sub * 8192);

  u32 e[8];
  {
    float4 a = m4[tid];
    float4 b = m4[tid + 1024];
    e[0] = encf(a.x); e[1] = encf(a.y); e[2] = encf(a.z); e[3] = encf(a.w);
    e[4] = encf(b.x); e[5] = encf(b.y); e[6] = encf(b.z); e[7] = encf(b.w);
  }

  __shared__ u32 wcnt[2][16];
  u32 T = 0u;
  for (int bit = 31; bit >= 0; --bit) {
    u32 Tt = T | (1u << bit);
    u32 c = 0;
#pragma unroll
    for (int k = 0; k < 8; ++k) c += (e[k] >= Tt) ? 1u : 0u;
#pragma unroll
    for (int off = 1; off < 64; off <<= 1) c += __shfl_xor(c, off, 64);
    if (lane == 0) wcnt[bit & 1][wid] = c;
    __syncthreads();
    u32 tot = 0;
#pragma unroll
    for (int w = 0; w < 16; ++w) tot += wcnt[bit & 1][w];
    if (tot >= 64u) T = Tt;
    // no second barrier: next round writes the OTHER buffer; the round-
    // (bit-1) barrier separates this round's reads from the bit-2 rewrite.
  }

  // emit candidates: enc >= T  (count >= 64 by loop invariant)
#pragma unroll
  for (int k = 0; k < 8; ++k) {
    if (e[k] >= T) {
      int q = k >> 2;                           // which float4
      int s = (tid + q * 1024) * 4 + (k & 3) + sub * 8192;
      u32 p = atomicAdd(&ccnt[bf], 1u);
      if (p < 2048u)
        cand[(long long)bf * 2048 + p] = ((u64)e[k] << 32) | (u64)(0xFFFFFFFFu - (u32)s);
    }
  }
}

// ---- top-64 stage 2: exact rank merge of candidates (keys unique).
// rank r = #(keys greater) -> identical (value desc, index asc) order as the
// FROZEN selection semantics. Candidate arrival order is irrelevant.
__global__ void __launch_bounds__(1024) k_top64_merge(const u64* __restrict__ cand,
                                                      const u32* __restrict__ ccnt,
                                                      int* __restrict__ top) {
  const int bf = blockIdx.x;
  const int tid = threadIdx.x;
  __shared__ u64 keys[2048];
  u32 n = ccnt[bf];
  if (n > 2048u) n = 2048u;
  for (u32 i = tid; i < n; i += 1024) keys[i] = cand[(long long)bf * 2048 + i];
  __syncthreads();
  for (u32 i = tid; i < n; i += 1024) {
    u64 mine = keys[i];
    int rank = 0;
    for (u32 j = 0; j < n; ++j) rank += (keys[j] > mine) ? 1 : 0;
    if (rank < 64)
      top[bf * 64 + rank] = (int)(0xFFFFFFFFu - (u32)(mine & 0xFFFFFFFFull));
  }
}

// ---- centers -> cov -> inv -> maha -> radix-select top-169 -> graph — FROZEN
__global__ void __launch_bounds__(256) k_graph(const int* __restrict__ top,
                                               float* __restrict__ out) {
  int bf = blockIdx.x;
  int tid = threadIdx.x;
  __shared__ float cy[64], cx[64];
  __shared__ float inv[4];
  __shared__ u32 keys[4096];
  __shared__ u32 bins[256];
  __shared__ u32 tie[4096];
  __shared__ u32 scal[4];
  if (tid < 64) {
    int idx = top[bf * 64 + tid];
    cy[tid] = (float)((idx >> 6) * 8 + 4);
    cx[tid] = (float)((idx & 63) * 8 + 4);
  }
  __syncthreads();
  if (tid == 0) {
    float sy = 0.f, sx = 0.f;
    for (int r = 0; r < 64; ++r) sy = __fadd_rn(sy, cy[r]);
    for (int r = 0; r < 64; ++r) sx = __fadd_rn(sx, cx[r]);
    float my = __fdiv_rn(sy, 64.0f), mx = __fdiv_rn(sx, 64.0f);
    float c00 = 0.f, c01 = 0.f, c11 = 0.f;
    for (int r = 0; r < 64; ++r) {
      float dy = __fsub_rn(cy[r], my);
      float dx = __fsub_rn(cx[r], mx);
      c00 = __fadd_rn(c00, __fmul_rn(dy, dy));
      c01 = __fadd_rn(c01, __fmul_rn(dy, dx));
      c11 = __fadd_rn(c11, __fmul_rn(dx, dx));
    }
    c00 = __fdiv_rn(c00, 63.0f); c01 = __fdiv_rn(c01, 63.0f); c11 = __fdiv_rn(c11, 63.0f);
    c00 = __fadd_rn(c00, 1e-6f); c11 = __fadd_rn(c11, 1e-6f);
    double det = (double)c00 * (double)c11 - (double)c01 * (double)c01;
    inv[0] = (float)((double)c11 / det);
    inv[1] = (float)(-(double)c01 / det);
    inv[2] = inv[1];
    inv[3] = (float)((double)c00 / det);
  }
  __syncthreads();
  float i00 = inv[0], i01 = inv[1], i10 = inv[2], i11 = inv[3];
  long long obase = (long long)bf * 4096;
  for (int e = tid; e < 4096; e += 256) {
    int q = e >> 6, r = e & 63;
    float d0 = __fsub_rn(cy[r], cy[q]);
    float d1 = __fsub_rn(cx[r], cx[q]);
    float v0 = __fadd_rn(__fadd_rn(0.0f, __fmul_rn(d0, i00)), __fmul_rn(d1, i10));
    float v1 = __fadd_rn(__fadd_rn(0.0f, __fmul_rn(d0, i01)), __fmul_rn(d1, i11));
    float p0 = __fmul_rn(v0, d0);
    float p1 = __fmul_rn(v1, d1);
    float s0 = __fsqrt_rn(p0);
    float s1 = __fsqrt_rn(p1);
    float mh = __fadd_rn(__fadd_rn(0.0f, s0), s1);
    u32 key;
    if (mh != mh) key = 0xFFFFFFFFu;
    else key = encf(-mh);
    keys[e] = key;
    out[obase + e] = 0.0f;
  }
  __syncthreads();

  u32 prefix = 0u, need = 169u;
  for (int pass = 0; pass < 4; ++pass) {
    int shift = 24 - pass * 8;
    if (tid == 0) { scal[2] = 0u; }
    bins[tid] = 0u;
    __syncthreads();
    for (int k = 0; k < 16; ++k) {
      u32 ky = keys[tid + (k << 8)];
      bool ok = (pass == 0) || ((ky >> (shift + 8)) == (prefix >> (shift + 8)));
      if (ok) atomicAdd(&bins[(ky >> shift) & 0xFFu], 1u);
    }
    __syncthreads();
    if (tid == 0) {
      u32 cum = 0; int d = 255;
      for (; d >= 0; --d) {
        u32 c = bins[d];
        if (cum + c >= need) break;
        cum += c;
      }
      if (d < 0) d = 0;
      scal[0] = prefix | ((u32)d << shift);
      scal[1] = need - cum;
    }
    __syncthreads();
    prefix = scal[0]; need = scal[1];
    __syncthreads();
  }

  for (int k = 0; k < 16; ++k) {
    int e = tid + (k << 8);
    u32 ky = keys[e];
    if (ky > prefix) out[obase + e] = 1.0f;
    else if (ky == prefix) {
      u32 p = atomicAdd(&scal[2], 1u);
      tie[p] = (u32)e;
    }
  }
  __syncthreads();
  int tc = (int)scal[2];
  for (int i = tid; i < tc; i += 256) {
    u32 ei = tie[i];
    int rank = 0;
    for (int j = 0; j < tc; ++j) rank += (tie[j] < ei);
    if (rank < (int)need) out[obase + ei] = 1.0f;
  }
}

extern "C" void kernel_launch(void* const* d_in, const int* in_sizes, int n_in,
                              void* d_out, int out_size, void* d_ws, size_t ws_size,
                              hipStream_t stream) {
  if (ws_size < (size_t)WS_NEED) return;
  const float* x = (const float*)d_in[0];
  float* out = (float*)d_out;
  char* ws = (char*)d_ws;
  u32* mm = (u32*)(ws + WS_MM);
  float* corr = (float*)(ws + WS_CORR);
  u32* ccnt = (u32*)(ws + WS_CCNT);
  u32* hist = (u32*)(ws + WS_HIST);
  int* top = (int*)(ws + WS_TOP);
  float* mag = (float*)(ws + WS_MAG);
  u32* mmpart = (u32*)(ws + WS_MMPART);
  u32* histc = (u32*)(ws + WS_HISTC);
  u64* cand = (u64*)d_out;   // scratch: fully overwritten by k_graph afterwards

  hipLaunchKernelGGL(k_init, dim3(300), dim3(256), 0, stream, histc, ccnt);
  hipLaunchKernelGGL(k_minmax_pass, dim3(2048), dim3(256), 0, stream, x, mmpart);
  hipLaunchKernelGGL(k_mm_reduce, dim3(4), dim3(256), 0, stream, mmpart, mm);
  hipLaunchKernelGGL(k_hist_pass, dim3(2048), dim3(256), 0, stream, x, mm, histc);
  hipLaunchKernelGGL(k_hist_reduce, dim3(4), dim3(320), 0, stream, histc, hist);
  hipLaunchKernelGGL(k_corr, dim3(4), dim3(128), 0, stream, hist, corr);
  hipLaunchKernelGGL(k_mag, dim3(7168), dim3(256), 0, stream, x, corr, mag);
  hipLaunchKernelGGL(k_top64_local, dim3(224), dim3(1024), 0, stream, mag, cand, ccnt);
  hipLaunchKernelGGL(k_top64_merge, dim3(28), dim3(1024), 0, stream, cand, ccnt, top);
  hipLaunchKernelGGL(k_graph, dim3(28), dim3(256), 0, stream, top, out);
}

// Round 10
// 225.236 us; speedup vs baseline: 1.5652x; 1.2618x over previous
//
#include <hip/hip_runtime.h>
#include <stdint.h>

// ============================================================================
// Motion_Relation_Mining — bit-exact replication of the JAX (CPU) reference.
//
// FROZEN (verified passing R0-R9, absmax 0.0): all f32 op sequences,
// NAN_POLICY_A, FMA-tanh, sequential reduce orders, selection key
// (enc(value)<<32)|~idx i.e. (value desc, index asc).
//
// R2: two-stage reductions replaced contended global atomics.
// R3: k_corr parallelized (scratch -> LDS, logs 100-wide).
// R4 (FAILED): ballot match-any histogram — unroll spilled enc[] to scratch.
// R8: bitwise threshold search, but 32 rounds x block-wide barrier over 16
//     waves + per-element global atomics = latency convoy (97us, VALU 7%).
// R9: threshold search made WAVE-AUTONOMOUS: each wave owns 4096 elements in
//     regs; rounds use only 6x shfl_xor (no LDS, no barriers, no inter-wave
//     coupling). One ccnt atomic per WAVE, ballot-compacted emission.
//     Candidate headroom 2x (1024 nominal vs 2048 cap; kills tie-overflow
//     hazard). k_hist_pass: 16-way lane-replicated sub-histograms — Gaussian
//     bin clustering made 64 lanes RMW one LDS address (64-way serial);
//     now 4-way across 16 banks. Integer counts identical.
// ============================================================================

typedef unsigned int u32;
typedef unsigned long long u64;

// sizes
#define BB 4
#define TT 8
#define CC 16
#define HWN 65536              // H*W
#define NF 7
#define FRAME 1048576LL        // C*H*W
#define NELF 7340032.0f        // nf*C*H*W per batch (exact in f32)
#define NPAIR 28
#define SEG 65536

// ws layout (bytes)
#define WS_MM 0                // u32[24] final min/max (encoded)
#define WS_CORR 128            // float[4]
#define WS_CCNT 144            // u32[28] candidate counters (zeroed by k_init)
#define WS_HIST 512            // u32[4][300] final histograms
#define WS_TOP 8192            // int[28][64]
#define WS_MAG 16384           // float[28][65536]
// overlaid inside WS_MAG region — fully consumed before k_mag writes:
#define WS_MMPART (WS_MAG)            // u32[2048][6]  = 48 KiB
#define WS_HISTC  (WS_MAG + 65536)    // u32[4][64][300] = 300 KiB
#define WS_NEED (16384 + 28LL*65536*4)
// candidate buffer lives in d_out (28*2048 u64 = 448 KiB = exact out size);
// k_graph fully overwrites d_out afterwards.

__device__ __forceinline__ u32 encf(float f) {
  u32 u = __float_as_uint(f);
  return (u & 0x80000000u) ? ~u : (u | 0x80000000u);
}
__device__ __forceinline__ float decf(u32 e) {
  u32 u = (e & 0x80000000u) ? (e ^ 0x80000000u) : ~e;
  return __uint_as_float(u);
}

// zero the histogram copies + candidate counters (graph replays each call)
__global__ void k_init(u32* histc, u32* ccnt) {
  int i = blockIdx.x * 256 + threadIdx.x;
  if (i < 76800) histc[i] = 0u;
  if (i < 28) ccnt[i] = 0u;
}

// ---- single pass over frames: per-batch min/max of x_t, x_t1, x_t*x_t1.
// float4 loads; min/max order-free; product elementwise -> exact.
__global__ void k_minmax_pass(const float* __restrict__ x, u32* __restrict__ part) {
  const int blk = blockIdx.x;            // 2048 blocks: 512 per batch
  const int b = blk >> 9;
  const long long w0 = (long long)(blk & 511) * 2048;
  const int tid = threadIdx.x;
  u32 mn0 = 0xFFFFFFFFu, mx0 = 0u, mn1 = 0xFFFFFFFFu, mx1 = 0u,
      mnp = 0xFFFFFFFFu, mxp = 0u;
  float4 pv0, pv1;
  for (int t = 0; t < 8; ++t) {
    const float4* fp = (const float4*)(x + ((long long)(b * TT + t)) * FRAME + w0);
    float4 v0 = fp[tid];
    float4 v1 = fp[tid + 256];
#define MM_COMP(vc, pc)                                                     \
    {                                                                       \
      u32 ev = encf(vc);                                                    \
      if (t < 7) { mn0 = min(mn0, ev); mx0 = max(mx0, ev); }                \
      if (t > 0) {                                                          \
        mn1 = min(mn1, ev); mx1 = max(mx1, ev);                             \
        u32 ep = encf(__fmul_rn(pc, vc));                                   \
        mnp = min(mnp, ep); mxp = max(mxp, ep);                             \
      }                                                                     \
    }
    MM_COMP(v0.x, pv0.x) MM_COMP(v0.y, pv0.y) MM_COMP(v0.z, pv0.z) MM_COMP(v0.w, pv0.w)
    MM_COMP(v1.x, pv1.x) MM_COMP(v1.y, pv1.y) MM_COMP(v1.z, pv1.z) MM_COMP(v1.w, pv1.w)
#undef MM_COMP
    pv0 = v0; pv1 = v1;
  }
  __shared__ u32 sm[6][256];
  sm[0][tid] = mn0; sm[1][tid] = mx0; sm[2][tid] = mn1;
  sm[3][tid] = mx1; sm[4][tid] = mnp; sm[5][tid] = mxp;
  __syncthreads();
  for (int st = 128; st > 0; st >>= 1) {
    if (tid < st) {
      sm[0][tid] = min(sm[0][tid], sm[0][tid + st]);
      sm[1][tid] = max(sm[1][tid], sm[1][tid + st]);
      sm[2][tid] = min(sm[2][tid], sm[2][tid + st]);
      sm[3][tid] = max(sm[3][tid], sm[3][tid + st]);
      sm[4][tid] = min(sm[4][tid], sm[4][tid + st]);
      sm[5][tid] = max(sm[5][tid], sm[5][tid + st]);
    }
    __syncthreads();
  }
  if (tid == 0) {
    u32* o = part + blk * 6;
    o[0] = sm[0][0]; o[1] = sm[1][0]; o[2] = sm[2][0];
    o[3] = sm[3][0]; o[4] = sm[4][0]; o[5] = sm[5][0];
  }
}

// 4 blocks (one per batch): reduce 512 partials -> mm[b*6..]
__global__ void k_mm_reduce(const u32* __restrict__ part, u32* __restrict__ mm) {
  const int b = blockIdx.x;
  const int tid = threadIdx.x;
  const u32* p0 = part + (b * 512 + tid) * 6;
  const u32* p1 = p0 + 256 * 6;
  __shared__ u32 sm[6][256];
  sm[0][tid] = min(p0[0], p1[0]); sm[1][tid] = max(p0[1], p1[1]);
  sm[2][tid] = min(p0[2], p1[2]); sm[3][tid] = max(p0[3], p1[3]);
  sm[4][tid] = min(p0[4], p1[4]); sm[5][tid] = max(p0[5], p1[5]);
  __syncthreads();
  for (int st = 128; st > 0; st >>= 1) {
    if (tid < st) {
      sm[0][tid] = min(sm[0][tid], sm[0][tid + st]);
      sm[1][tid] = max(sm[1][tid], sm[1][tid + st]);
      sm[2][tid] = min(sm[2][tid], sm[2][tid + st]);
      sm[3][tid] = max(sm[3][tid], sm[3][tid + st]);
      sm[4][tid] = min(sm[4][tid], sm[4][tid + st]);
      sm[5][tid] = max(sm[5][tid], sm[5][tid + st]);
    }
    __syncthreads();
  }
  if (tid == 0)
    for (int i = 0; i < 6; ++i) mm[b * 6 + i] = sm[i][0];
}

__device__ __forceinline__ int bin_of(float v, float vmin, float den) {
  float tt = __fsub_rn(v, vmin);
  float q = __fdiv_rn(tt, den);
  float z = __fmul_rn(q, 100.0f);
  z = fminf(fmaxf(z, 0.0f), 99.0f);
  return (int)z;
}

// ---- single pass over frames: 16-way lane-replicated LDS sub-histograms
// (R9: kills 64-way same-address serialization on Gaussian-centered bins),
// then flush to one of 64 global copies per batch.
__global__ void k_hist_pass(const float* __restrict__ x, const u32* __restrict__ mm,
                            u32* __restrict__ histc) {
  __shared__ u32 h[300 * 16];            // h[bin*16 + (lane&15)]
  for (int i = threadIdx.x; i < 4800; i += 256) h[i] = 0u;
  __syncthreads();
  const int blk = blockIdx.x;
  const int b = blk >> 9;
  const long long w0 = (long long)(blk & 511) * 2048;
  const int tid = threadIdx.x;
  const int sub = tid & 15;
  float mn_t = decf(mm[6 * b + 0]), den_t = __fsub_rn(decf(mm[6 * b + 1]), decf(mm[6 * b + 0]));
  float mn_1 = decf(mm[6 * b + 2]), den_1 = __fsub_rn(decf(mm[6 * b + 3]), decf(mm[6 * b + 2]));
  float mn_p = decf(mm[6 * b + 4]), den_p = __fsub_rn(decf(mm[6 * b + 5]), decf(mm[6 * b + 4]));
  float prev[8];
  for (int t = 0; t < 8; ++t) {
    const float* fp = x + ((long long)(b * TT + t)) * FRAME + w0 + tid;
#pragma unroll
    for (int k = 0; k < 8; ++k) {
      float v = fp[k << 8];
      if (t < 7) atomicAdd(&h[bin_of(v, mn_t, den_t) * 16 + sub], 1u);
      if (t > 0) {
        atomicAdd(&h[(100 + bin_of(v, mn_1, den_1)) * 16 + sub], 1u);
        float p = __fmul_rn(prev[k], v);
        atomicAdd(&h[(200 + bin_of(p, mn_p, den_p)) * 16 + sub], 1u);
      }
      prev[k] = v;
    }
  }
  __syncthreads();
  u32* dst = histc + ((b << 6) + (blk & 63)) * 300;
  for (int i = threadIdx.x; i < 300; i += 256) {
    u32 s = 0;
#pragma unroll
    for (int c = 0; c < 16; ++c) s += h[i * 16 + c];
    atomicAdd(&dst[i], s);
  }
}

// 4 blocks x 320 threads: hist[b*300+i] = sum of 64 copies (exact integers)
__global__ void k_hist_reduce(const u32* __restrict__ histc, u32* __restrict__ hist) {
  int b = blockIdx.x, i = threadIdx.x;
  if (i < 300) {
    const u32* src = histc + (b << 6) * 300 + i;
    u32 s = 0;
    for (int c = 0; c < 64; ++c) s += src[c * 300];
    hist[b * 300 + i] = s;
  }
}

// Eigen/XLA fast-tanh rational interpolant (FMA form) — FROZEN
__device__ float tanh_emul(float a) {
  const float kClamp = 7.90531110763549805f;
  float xx = fminf(fmaxf(a, -kClamp), kClamp);
  float x2 = __fmul_rn(xx, xx);
  float p = __fmaf_rn(x2, -2.76076847742355e-16f, 2.00018790482477e-13f);
  p = __fmaf_rn(x2, p, -8.60467152213735e-11f);
  p = __fmaf_rn(x2, p, 5.12229709037114e-08f);
  p = __fmaf_rn(x2, p, 1.48572235717979e-05f);
  p = __fmaf_rn(x2, p, 6.37261928875436e-04f);
  p = __fmaf_rn(x2, p, 4.89352455891786e-03f);
  p = __fmul_rn(xx, p);
  float q = __fmaf_rn(x2, 1.19825839466702e-06f, 1.18534705686654e-04f);
  q = __fmaf_rn(x2, q, 2.26843463243900e-03f);
  q = __fmaf_rn(x2, q, 4.89352518554385e-03f);
  float r = __fdiv_rn(p, q);
  if (fabsf(a) < 0.0004f) r = a;
  return r;
}

// ---- mi + corr per batch. Parallel per-bin terms, FROZEN sequential chains.
__global__ void __launch_bounds__(128) k_corr(const u32* __restrict__ hist,
                                              float* __restrict__ corr) {
  const int b = blockIdx.x;
  const int tid = threadIdx.x;
  __shared__ float shx[100], shx1[100], sterm[100];
  __shared__ float ssum[3];
  const u32* HX = hist + b * 300;
  const u32* HX1 = HX + 100;
  const u32* HJ = HX + 200;

  if (tid < 100) {
    shx[tid] = __fdiv_rn((float)HX[tid], NELF);
    shx1[tid] = __fdiv_rn((float)HX1[tid], NELF);
  }
  __syncthreads();
  if (tid == 0) {
    float Sj = 0.0f;
    for (int i = 0; i < 100; ++i) Sj = __fadd_rn(Sj, (float)HJ[i]);
    float Sx = 0.0f, Sx1 = 0.0f;
    for (int i = 0; i < 100; ++i) Sx = __fadd_rn(Sx, shx[i]);
    for (int i = 0; i < 100; ++i) Sx1 = __fadd_rn(Sx1, shx1[i]);
    ssum[0] = Sj; ssum[1] = Sx; ssum[2] = Sx1;
  }
  __syncthreads();
  if (tid < 100) {
    float Sj = ssum[0], Sx = ssum[1], Sx1 = ssum[2];
    float pj = __fdiv_rn((float)HJ[tid], Sj);
    float px = __fdiv_rn(shx[tid], Sx);
    float px1 = __fdiv_rn(shx1[tid], Sx1);
    float la = (float)log((double)__fadd_rn(pj, 1e-10f));
    float lb = (float)log((double)__fadd_rn(__fmul_rn(px, px1), 1e-10f));
    sterm[tid] = __fmul_rn(pj, __fsub_rn(la, lb));
  }
  __syncthreads();
  if (tid == 0) {
    float mi = 0.0f;
    for (int i = 0; i < 100; ++i) mi = __fadd_rn(mi, sterm[i]);
    float lm = (float)log((double)mi);
    float th = tanh_emul(lm);
    float num = (float)exp(0.8);
    corr[b] = __fdiv_rn(num, th);
  }
}

// ---- mag[b,f,s] = sequential f32 sum over c of fl(fl(x1-x0)+corr[b]) — FROZEN
__global__ void k_mag(const float* __restrict__ x, const float* __restrict__ corr,
                      float* __restrict__ mag) {
  int gid = blockIdx.x * 256 + threadIdx.x;
  int bf = gid >> 16;
  int s = gid & 65535;
  int b = bf / NF, f = bf % NF;
  int g = s >> 6, i = (s >> 3) & 7, j = s & 7;
  int gy = g >> 5, gx = g & 31;
  int hw = (gy * 8 + i) * 256 + gx * 8 + j;
  const float cb = corr[b];
  long long base = ((long long)(b * TT + f)) * FRAME + hw;
  float acc = 0.0f;
  for (int c = 0; c < CC; ++c) {
    float a0 = x[base + (long long)c * HWN];
    float a1 = x[base + FRAME + (long long)c * HWN];
    acc = __fadd_rn(acc, __fadd_rn(__fsub_rn(a1, a0), cb));
  }
  mag[gid] = acc;
}

// ---- top-64 stage 1 (R9): 4 blocks per (b,f) x 4 waves; each WAVE owns
// 4096 elements in registers and finds its own 64th-largest via 32-round
// bitwise threshold search — shfl-only, ZERO barriers, ZERO LDS.
// Any global-top-64 element v has <=63 greater elements globally, hence
// <=63 in its wave's subset, hence v >= wave-T -> emitted (exact superset).
// Emission: one ccnt atomic per wave + ballot-compacted writes.
__global__ void __launch_bounds__(256) k_top64_local(const float* __restrict__ mag,
                                                     u64* __restrict__ cand,
                                                     u32* __restrict__ ccnt) {
  const int blk = blockIdx.x;        // 112: 4 per bf
  const int bf = blk >> 2;
  const int sub = blk & 3;           // 16384 elements per block
  const int tid = threadIdx.x;
  const int lane = tid & 63;
  const int wid = tid >> 6;          // 0..3
  const int wbase_elem = sub * 16384 + wid * 4096;
  const float4* m4 = (const float4*)(mag + (long long)bf * SEG + wbase_elem);

  u32 e[64];
#pragma unroll
  for (int k = 0; k < 16; ++k) {
    float4 v = m4[k * 64 + lane];    // wave reads 1KB contiguous per k
    e[4 * k + 0] = encf(v.x); e[4 * k + 1] = encf(v.y);
    e[4 * k + 2] = encf(v.z); e[4 * k + 3] = encf(v.w);
  }

  // 32-round bitwise search for the wave's 64th-largest encoded value
  u32 T = 0u;
  for (int bit = 31; bit >= 0; --bit) {
    u32 Tt = T | (1u << bit);
    u32 c = 0;
#pragma unroll
    for (int k = 0; k < 64; ++k) c += (e[k] >= Tt) ? 1u : 0u;
#pragma unroll
    for (int off = 1; off < 64; off <<= 1) c += __shfl_xor(c, off, 64);
    if (c >= 64u) T = Tt;            // uniform across wave (full butterfly)
  }

  // wave total & base reservation (ONE atomic per wave)
  u32 mycnt = 0;
#pragma unroll
  for (int k = 0; k < 64; ++k) mycnt += (e[k] >= T) ? 1u : 0u;
  u32 wtot = mycnt;
#pragma unroll
  for (int off = 1; off < 64; off <<= 1) wtot += __shfl_xor(wtot, off, 64);
  u32 rbase = 0;
  if (lane == 0) rbase = atomicAdd(&ccnt[bf], wtot);
  rbase = __shfl(rbase, 0, 64);

  // ballot-compacted emission
  u32 run = rbase;
  const u64 below = (lane == 0) ? 0ull : (~0ull >> (64 - lane));
#pragma unroll
  for (int k = 0; k < 64; ++k) {
    bool cnd = (e[k] >= T);
    u64 mask = __ballot(cnd);
    if (cnd) {
      u32 off = run + (u32)__popcll(mask & below);
      if (off < 2048u) {
        int s = wbase_elem + (k >> 2) * 256 + lane * 4 + (k & 3);
        cand[(long long)bf * 2048 + off] =
            ((u64)e[k] << 32) | (u64)(0xFFFFFFFFu - (u32)s);
      }
    }
    run += (u32)__popcll(mask);
  }
}

// ---- top-64 stage 2: exact rank merge of candidates (keys unique).
// rank r = #(keys greater) -> identical (value desc, index asc) order as the
// FROZEN selection semantics. Candidate arrival order is irrelevant.
__global__ void __launch_bounds__(1024) k_top64_merge(const u64* __restrict__ cand,
                                                      const u32* __restrict__ ccnt,
                                                      int* __restrict__ top) {
  const int bf = blockIdx.x;
  const int tid = threadIdx.x;
  __shared__ u64 keys[2048];
  u32 n = ccnt[bf];
  if (n > 2048u) n = 2048u;
  for (u32 i = tid; i < n; i += 1024) keys[i] = cand[(long long)bf * 2048 + i];
  __syncthreads();
  for (u32 i = tid; i < n; i += 1024) {
    u64 mine = keys[i];
    int rank = 0;
    for (u32 j = 0; j < n; ++j) rank += (keys[j] > mine) ? 1 : 0;
    if (rank < 64)
      top[bf * 64 + rank] = (int)(0xFFFFFFFFu - (u32)(mine & 0xFFFFFFFFull));
  }
}

// ---- centers -> cov -> inv -> maha -> radix-select top-169 -> graph — FROZEN
__global__ void __launch_bounds__(256) k_graph(const int* __restrict__ top,
                                               float* __restrict__ out) {
  int bf = blockIdx.x;
  int tid = threadIdx.x;
  __shared__ float cy[64], cx[64];
  __shared__ float inv[4];
  __shared__ u32 keys[4096];
  __shared__ u32 bins[256];
  __shared__ u32 tie[4096];
  __shared__ u32 scal[4];
  if (tid < 64) {
    int idx = top[bf * 64 + tid];
    cy[tid] = (float)((idx >> 6) * 8 + 4);
    cx[tid] = (float)((idx & 63) * 8 + 4);
  }
  __syncthreads();
  if (tid == 0) {
    float sy = 0.f, sx = 0.f;
    for (int r = 0; r < 64; ++r) sy = __fadd_rn(sy, cy[r]);
    for (int r = 0; r < 64; ++r) sx = __fadd_rn(sx, cx[r]);
    float my = __fdiv_rn(sy, 64.0f), mx = __fdiv_rn(sx, 64.0f);
    float c00 = 0.f, c01 = 0.f, c11 = 0.f;
    for (int r = 0; r < 64; ++r) {
      float dy = __fsub_rn(cy[r], my);
      float dx = __fsub_rn(cx[r], mx);
      c00 = __fadd_rn(c00, __fmul_rn(dy, dy));
      c01 = __fadd_rn(c01, __fmul_rn(dy, dx));
      c11 = __fadd_rn(c11, __fmul_rn(dx, dx));
    }
    c00 = __fdiv_rn(c00, 63.0f); c01 = __fdiv_rn(c01, 63.0f); c11 = __fdiv_rn(c11, 63.0f);
    c00 = __fadd_rn(c00, 1e-6f); c11 = __fadd_rn(c11, 1e-6f);
    double det = (double)c00 * (double)c11 - (double)c01 * (double)c01;
    inv[0] = (float)((double)c11 / det);
    inv[1] = (float)(-(double)c01 / det);
    inv[2] = inv[1];
    inv[3] = (float)((double)c00 / det);
  }
  __syncthreads();
  float i00 = inv[0], i01 = inv[1], i10 = inv[2], i11 = inv[3];
  long long obase = (long long)bf * 4096;
  for (int e = tid; e < 4096; e += 256) {
    int q = e >> 6, r = e & 63;
    float d0 = __fsub_rn(cy[r], cy[q]);
    float d1 = __fsub_rn(cx[r], cx[q]);
    float v0 = __fadd_rn(__fadd_rn(0.0f, __fmul_rn(d0, i00)), __fmul_rn(d1, i10));
    float v1 = __fadd_rn(__fadd_rn(0.0f, __fmul_rn(d0, i01)), __fmul_rn(d1, i11));
    float p0 = __fmul_rn(v0, d0);
    float p1 = __fmul_rn(v1, d1);
    float s0 = __fsqrt_rn(p0);
    float s1 = __fsqrt_rn(p1);
    float mh = __fadd_rn(__fadd_rn(0.0f, s0), s1);
    u32 key;
    if (mh != mh) key = 0xFFFFFFFFu;
    else key = encf(-mh);
    keys[e] = key;
    out[obase + e] = 0.0f;
  }
  __syncthreads();

  u32 prefix = 0u, need = 169u;
  for (int pass = 0; pass < 4; ++pass) {
    int shift = 24 - pass * 8;
    if (tid == 0) { scal[2] = 0u; }
    bins[tid] = 0u;
    __syncthreads();
    for (int k = 0; k < 16; ++k) {
      u32 ky = keys[tid + (k << 8)];
      bool ok = (pass == 0) || ((ky >> (shift + 8)) == (prefix >> (shift + 8)));
      if (ok) atomicAdd(&bins[(ky >> shift) & 0xFFu], 1u);
    }
    __syncthreads();
    if (tid == 0) {
      u32 cum = 0; int d = 255;
      for (; d >= 0; --d) {
        u32 c = bins[d];
        if (cum + c >= need) break;
        cum += c;
      }
      if (d < 0) d = 0;
      scal[0] = prefix | ((u32)d << shift);
      scal[1] = need - cum;
    }
    __syncthreads();
    prefix = scal[0]; need = scal[1];
    __syncthreads();
  }

  for (int k = 0; k < 16; ++k) {
    int e = tid + (k << 8);
    u32 ky = keys[e];
    if (ky > prefix) out[obase + e] = 1.0f;
    else if (ky == prefix) {
      u32 p = atomicAdd(&scal[2], 1u);
      tie[p] = (u32)e;
    }
  }
  __syncthreads();
  int tc = (int)scal[2];
  for (int i = tid; i < tc; i += 256) {
    u32 ei = tie[i];
    int rank = 0;
    for (int j = 0; j < tc; ++j) rank += (tie[j] < ei);
    if (rank < (int)need) out[obase + ei] = 1.0f;
  }
}

extern "C" void kernel_launch(void* const* d_in, const int* in_sizes, int n_in,
                              void* d_out, int out_size, void* d_ws, size_t ws_size,
                              hipStream_t stream) {
  if (ws_size < (size_t)WS_NEED) return;
  const float* x = (const float*)d_in[0];
  float* out = (float*)d_out;
  char* ws = (char*)d_ws;
  u32* mm = (u32*)(ws + WS_MM);
  float* corr = (float*)(ws + WS_CORR);
  u32* ccnt = (u32*)(ws + WS_CCNT);
  u32* hist = (u32*)(ws + WS_HIST);
  int* top = (int*)(ws + WS_TOP);
  float* mag = (float*)(ws + WS_MAG);
  u32* mmpart = (u32*)(ws + WS_MMPART);
  u32* histc = (u32*)(ws + WS_HISTC);
  u64* cand = (u64*)d_out;   // scratch: fully overwritten by k_graph afterwards

  hipLaunchKernelGGL(k_init, dim3(300), dim3(256), 0, stream, histc, ccnt);
  hipLaunchKernelGGL(k_minmax_pass, dim3(2048), dim3(256), 0, stream, x, mmpart);
  hipLaunchKernelGGL(k_mm_reduce, dim3(4), dim3(256), 0, stream, mmpart, mm);
  hipLaunchKernelGGL(k_hist_pass, dim3(2048), dim3(256), 0, stream, x, mm, histc);
  hipLaunchKernelGGL(k_hist_reduce, dim3(4), dim3(320), 0, stream, histc, hist);
  hipLaunchKernelGGL(k_corr, dim3(4), dim3(128), 0, stream, hist, corr);
  hipLaunchKernelGGL(k_mag, dim3(7168), dim3(256), 0, stream, x, corr, mag);
  hipLaunchKernelGGL(k_top64_local, dim3(112), dim3(256), 0, stream, mag, cand, ccnt);
  hipLaunchKernelGGL(k_top64_merge, dim3(28), dim3(1024), 0, stream, cand, ccnt, top);
  hipLaunchKernelGGL(k_graph, dim3(28), dim3(256), 0, stream, top, out);
}